// Round 1
// baseline (228.684 us; speedup 1.0000x reference)
//
#include <hip/hip_runtime.h>

// BilinearInterpolation (spatial transformer sampling)
// image: [32, 512, 512, 4] f32 (NHWC, C=4 -> one pixel == one float4)
// affine: [32, 6] f32
// out:   [32, 512, 512, 4] f32

#define IMG_H 512
#define IMG_W 512
#define OUT_H 512
#define OUT_W 512
#define NBATCH 32

__global__ __launch_bounds__(256) void bilerp_kernel(
    const float* __restrict__ image,
    const float* __restrict__ affine,
    float* __restrict__ out)
{
    const int n = blockIdx.x * blockDim.x + threadIdx.x;  // pixel index in [0, OUT_H*OUT_W)
    const int b = blockIdx.y;

    const int i = n >> 9;    // output row   (OUT_W == 512)
    const int j = n & 511;   // output col

    // normalized grid coords, linspace(-1, 1, 512) -> step = 2/511
    const float step = 2.0f / 511.0f;
    const float xn = -1.0f + step * (float)j;
    const float yn = -1.0f + step * (float)i;

    // per-batch affine (6 floats) — tiny, L2/L1 resident
    const float* t = affine + b * 6;
    float x = t[0] * xn + t[1] * yn + t[2];
    float y = t[3] * xn + t[4] * yn + t[5];

    // to image coords (scale by full W/H, no -1 — matches reference)
    x = 0.5f * (x + 1.0f) * (float)IMG_W;
    y = 0.5f * (y + 1.0f) * (float)IMG_H;

    // corners: truncation toward zero (matches numpy astype(int32))
    int x_min = (int)x;
    int y_min = (int)y;
    int x_max = x_min + 1;
    int y_max = y_min + 1;
    x_min = min(max(x_min, 0), IMG_W - 1);
    x_max = min(max(x_max, 0), IMG_W - 1);
    y_min = min(max(y_min, 0), IMG_H - 1);
    y_max = min(max(y_max, 0), IMG_H - 1);

    // weights from CLIPPED corner coords (reference clips before computing weights)
    const float xmf = (float)x_min, xMf = (float)x_max;
    const float ymf = (float)y_min, yMf = (float)y_max;
    const float aA = (xMf - x) * (yMf - y);
    const float aB = (xMf - x) * (y - ymf);
    const float aC = (x - xmf) * (yMf - y);
    const float aD = (x - xmf) * (y - ymf);

    const float4* img = (const float4*)image + (size_t)b * (IMG_H * IMG_W);
    const float4 pA = img[y_min * IMG_W + x_min];
    const float4 pB = img[y_max * IMG_W + x_min];
    const float4 pC = img[y_min * IMG_W + x_max];
    const float4 pD = img[y_max * IMG_W + x_max];

    float4 o;
    o.x = pA.x * aA + pB.x * aB + pC.x * aC + pD.x * aD;
    o.y = pA.y * aA + pB.y * aB + pC.y * aC + pD.y * aD;
    o.z = pA.z * aA + pB.z * aB + pC.z * aC + pD.z * aD;
    o.w = pA.w * aA + pB.w * aB + pC.w * aC + pD.w * aD;

    ((float4*)out)[(size_t)b * (OUT_H * OUT_W) + n] = o;
}

extern "C" void kernel_launch(void* const* d_in, const int* in_sizes, int n_in,
                              void* d_out, int out_size, void* d_ws, size_t ws_size,
                              hipStream_t stream)
{
    const float* image  = (const float*)d_in[0];   // 32*512*512*4
    const float* affine = (const float*)d_in[1];   // 32*6
    float* out = (float*)d_out;

    dim3 block(256);
    dim3 grid((OUT_H * OUT_W) / 256, NBATCH);
    bilerp_kernel<<<grid, block, 0, stream>>>(image, affine, out);
}

// Round 3
// 220.175 us; speedup vs baseline: 1.0386x; 1.0386x over previous
//
#include <hip/hip_runtime.h>

// BilinearInterpolation (spatial transformer sampling)
// image: [32, 512, 512, 4] f32 (NHWC, C=4 -> one pixel == one native float4)
// affine: [32, 6] f32
// out:   [32, 512, 512, 4] f32
//
// Block = 64(x) x 4(y) output tile: vertical corner-row reuse is captured
// inside the block (L1), not left to cross-XCD L2 (per-XCD L2s are not
// shared, and adjacent-row blocks land on different XCDs).

#define IMG_H 512
#define IMG_W 512
#define OUT_H 512
#define OUT_W 512
#define NBATCH 32
#define TILE_X 64
#define TILE_Y 4

// native clang vector — required by __builtin_nontemporal_store
typedef float fx4 __attribute__((ext_vector_type(4)));

__global__ __launch_bounds__(256) void bilerp_kernel(
    const float* __restrict__ image,
    const float* __restrict__ affine,
    float* __restrict__ out)
{
    const int tx = threadIdx.x & 63;        // 0..63  (one wave spans a 64-wide row)
    const int ty = threadIdx.x >> 6;        // 0..3
    const int j = blockIdx.x * TILE_X + tx; // output col
    const int i = blockIdx.y * TILE_Y + ty; // output row
    const int b = blockIdx.z;

    // normalized grid coords, linspace(-1, 1, 512) -> step = 2/511
    const float step = 2.0f / 511.0f;
    const float xn = -1.0f + step * (float)j;
    const float yn = -1.0f + step * (float)i;

    // per-batch affine (6 floats) — tiny, cache resident
    const float* t = affine + b * 6;
    float x = t[0] * xn + t[1] * yn + t[2];
    float y = t[3] * xn + t[4] * yn + t[5];

    // to image coords (scale by full W/H, no -1 — matches reference)
    x = 0.5f * (x + 1.0f) * (float)IMG_W;
    y = 0.5f * (y + 1.0f) * (float)IMG_H;

    // corners: truncation toward zero (matches numpy astype(int32))
    int x_min = (int)x;
    int y_min = (int)y;
    int x_max = x_min + 1;
    int y_max = y_min + 1;
    x_min = min(max(x_min, 0), IMG_W - 1);
    x_max = min(max(x_max, 0), IMG_W - 1);
    y_min = min(max(y_min, 0), IMG_H - 1);
    y_max = min(max(y_max, 0), IMG_H - 1);

    // weights from CLIPPED corner coords (reference clips before weights)
    const float xmf = (float)x_min, xMf = (float)x_max;
    const float ymf = (float)y_min, yMf = (float)y_max;
    const float aA = (xMf - x) * (yMf - y);
    const float aB = (xMf - x) * (y - ymf);
    const float aC = (x - xmf) * (yMf - y);
    const float aD = (x - xmf) * (y - ymf);

    const fx4* img = (const fx4*)image + (size_t)b * (IMG_H * IMG_W);
    const fx4 pA = img[y_min * IMG_W + x_min];
    const fx4 pB = img[y_max * IMG_W + x_min];
    const fx4 pC = img[y_min * IMG_W + x_max];
    const fx4 pD = img[y_max * IMG_W + x_max];

    fx4 o = pA * aA + pB * aB + pC * aC + pD * aD;

    // output is never re-read: non-temporal store keeps L2 for image lines
    fx4* op = (fx4*)out + (size_t)b * (OUT_H * OUT_W) + (size_t)i * OUT_W + j;
    __builtin_nontemporal_store(o, op);
}

extern "C" void kernel_launch(void* const* d_in, const int* in_sizes, int n_in,
                              void* d_out, int out_size, void* d_ws, size_t ws_size,
                              hipStream_t stream)
{
    const float* image  = (const float*)d_in[0];   // 32*512*512*4
    const float* affine = (const float*)d_in[1];   // 32*6
    float* out = (float*)d_out;

    dim3 block(256);
    dim3 grid(OUT_W / TILE_X, OUT_H / TILE_Y, NBATCH);
    bilerp_kernel<<<grid, block, 0, stream>>>(image, affine, out);
}